// Round 1
// baseline (1158.340 us; speedup 1.0000x reference)
//
#include <hip/hip_runtime.h>

using half8  = __attribute__((ext_vector_type(8))) _Float16;
using half4v = __attribute__((ext_vector_type(4))) _Float16;
using f32x4  = __attribute__((ext_vector_type(4))) float;

#define MFMA16(a,b,c) __builtin_amdgcn_mfma_f32_16x16x32_f16((a),(b),(c),0,0,0)

__device__ __forceinline__ float fexp_(float x){ return exp2f(x * 1.4426950408889634f); }
__device__ __forceinline__ float sig_(float x){ return __builtin_amdgcn_rcpf(1.0f + fexp_(-x)); }
__device__ __forceinline__ float tanh_(float x){
  float t = fexp_(-2.0f * fabsf(x));
  float r = (1.0f - t) * __builtin_amdgcn_rcpf(1.0f + t);
  return copysignf(r, x);
}

// ---------------- K0: weight transposes / fp16 packing ----------------
// wkt : [1024 g][320 k]  (k 300..319 zero)            WkT[g][k] = Wk[k][g]
// wrtb: [4 jt][128? no: 256 r][256 k]  r = 64*gate+i  <-> g = 256*gate + 64*jt + i
// wdt : [256 d][512 k]                                 WdT[d][k] = Wd[k][d]
__global__ void k0_prep(const float* __restrict__ Wk, const float* __restrict__ Wr,
                        const float* __restrict__ Wd, _Float16* __restrict__ wkt,
                        _Float16* __restrict__ wrtb, _Float16* __restrict__ wdt)
{
  int i = blockIdx.x * 256 + threadIdx.x;
  if (i < 1024*320) {
    int g = i / 320, k = i - g*320;
    wkt[i] = (_Float16)((k < 300) ? Wk[k*1024 + g] : 0.0f);
  }
  if (i < 4*256*256) {
    int jt = i >> 16, r = (i >> 8) & 255, k = i & 255;
    int g = ((r >> 6) << 8) + (jt << 6) + (r & 63);
    wrtb[i] = (_Float16)Wr[k*1024 + g];
  }
  if (i < 256*512) {
    int d = i >> 9, k = i & 511;
    wdt[i] = (_Float16)Wd[k*256 + d];
  }
}

// ---------------- K1: embW = emb @ Wk + b  (gate-blocked fp16) ----------------
// embw[jt][v][c], c = 64*gate + i  <-> gatecol g = 256*gate + 64*jt + i
__global__ __launch_bounds__(512, 2) void k1_embw(
    const float* __restrict__ emb, const float* __restrict__ bias,
    const _Float16* __restrict__ wkt, _Float16* __restrict__ embw)
{
  __shared__ _Float16 a_s[1024][40];
  __shared__ _Float16 e_s[64][40];
  const int tid = threadIdx.x;
  const int wv = tid >> 6, ln = tid & 63, l16 = ln & 15, lq = ln >> 4;
  const int v0 = blockIdx.x * 64;

  f32x4 acc[8][4];
  #pragma unroll
  for (int ml=0;ml<8;++ml)
    #pragma unroll
    for (int nt=0;nt<4;++nt){ f32x4 z0; z0[0]=0.f;z0[1]=0.f;z0[2]=0.f;z0[3]=0.f; acc[ml][nt]=z0; }

  const int evv = tid >> 2;   // 0..63 when tid<256
  const int ekq = tid & 3;

  for (int c = 0; c < 10; ++c) {
    { // stage WkT chunk: rows 2*tid, 2*tid+1, cols [32c,32c+32)
      const uint4* sp  = (const uint4*)(wkt + (size_t)(2*tid)*320 + 32*c);
      uint4 r0=sp[0], r1=sp[1], r2=sp[2], r3=sp[3];
      const uint4* sp2 = (const uint4*)(wkt + (size_t)(2*tid+1)*320 + 32*c);
      uint4 r4=sp2[0], r5=sp2[1], r6=sp2[2], r7=sp2[3];
      uint4* dq  = (uint4*)&a_s[2*tid][0];
      dq[0]=r0; dq[1]=r1; dq[2]=r2; dq[3]=r3;
      uint4* dq2 = (uint4*)&a_s[2*tid+1][0];
      dq2[0]=r4; dq2[1]=r5; dq2[2]=r6; dq2[3]=r7;
    }
    if (tid < 256) { // stage emb chunk (f32 -> fp16), zero-pad k>=300
      int vsrc = v0 + evv; if (vsrc > 19999) vsrc = 19999;
      float f0,f1,f2,f3,f4,f5,f6,f7;
      if (c < 9) {
        const float4* sp = (const float4*)(emb + (size_t)vsrc*300 + 32*c + 8*ekq);
        float4 fa = sp[0], fb = sp[1];
        f0=fa.x; f1=fa.y; f2=fa.z; f3=fa.w; f4=fb.x; f5=fb.y; f6=fb.z; f7=fb.w;
      } else {
        const float* sp = emb + (size_t)vsrc*300;
        int k0 = 288 + 8*ekq;
        f0 = (k0+0<300)? sp[k0+0] : 0.f;  f1 = (k0+1<300)? sp[k0+1] : 0.f;
        f2 = (k0+2<300)? sp[k0+2] : 0.f;  f3 = (k0+3<300)? sp[k0+3] : 0.f;
        f4 = (k0+4<300)? sp[k0+4] : 0.f;  f5 = (k0+5<300)? sp[k0+5] : 0.f;
        f6 = (k0+6<300)? sp[k0+6] : 0.f;  f7 = (k0+7<300)? sp[k0+7] : 0.f;
      }
      half8 hv;
      hv[0]=(_Float16)f0; hv[1]=(_Float16)f1; hv[2]=(_Float16)f2; hv[3]=(_Float16)f3;
      hv[4]=(_Float16)f4; hv[5]=(_Float16)f5; hv[6]=(_Float16)f6; hv[7]=(_Float16)f7;
      *(half8*)&e_s[evv][8*ekq] = hv;
    }
    __syncthreads();
    half8 bf[4];
    #pragma unroll
    for (int nt=0;nt<4;++nt) bf[nt] = *(const half8*)&e_s[16*nt + l16][8*lq];
    #pragma unroll
    for (int ml=0;ml<8;++ml) {
      half8 af = *(const half8*)&a_s[16*(8*wv+ml) + l16][8*lq];
      #pragma unroll
      for (int nt=0;nt<4;++nt) acc[ml][nt] = MFMA16(af, bf[nt], acc[ml][nt]);
    }
    __syncthreads();
  }
  // epilogue: +bias, cvt fp16, store gate-blocked
  #pragma unroll
  for (int ml=0;ml<8;++ml) {
    int g0 = 16*(8*wv+ml) + 4*lq;                 // + reg
    float4 bv = *(const float4*)&bias[g0];
    float bvr[4] = {bv.x,bv.y,bv.z,bv.w};
    int jt = (g0 >> 6) & 3;
    int c0 = ((g0 >> 8) << 6) + (g0 & 63);
    #pragma unroll
    for (int nt=0;nt<4;++nt) {
      int v = v0 + 16*nt + l16;
      if (v < 20000) {
        half4v hv;
        hv[0]=(_Float16)(acc[ml][nt][0]+bvr[0]);
        hv[1]=(_Float16)(acc[ml][nt][1]+bvr[1]);
        hv[2]=(_Float16)(acc[ml][nt][2]+bvr[2]);
        hv[3]=(_Float16)(acc[ml][nt][3]+bvr[3]);
        *(half4v*)&embw[((size_t)jt*20000 + v)*256 + c0] = hv;
      }
    }
  }
}

// ---------------- K2: fused bi-LSTM + dense + attention, 1 block = 1 card ----------------
// 96 rows: 0..47 fw (paths padded to 48), 48..95 bw. z computed transposed:
// zT = WrT(A) x hT(B): acc m = gatecol (4 gates lane-local), n = seq.
#define K2_LOAD_W(JT,KQ) {                                                                 \
    const uint4* wp = (const uint4*)(wrtb + ((size_t)((JT)*256 + ws_row))*256 + (KQ)*64 + ws_h*32); \
    wR[0]=wp[0]; wR[1]=wp[1]; wR[2]=wp[2]; wR[3]=wp[3]; }
#define K2_WRITE_W() {                                                                     \
    uint4* wq = (uint4*)&w_s[ws_row][ws_h*32];                                             \
    wq[0]=wR[0]; wq[1]=wR[1]; wq[2]=wR[2]; wq[3]=wR[3]; }
#define K2_LOAD_E(JT) if (tid < 384) {                                                     \
    const uint4* ep = (const uint4*)(embw + ((size_t)(JT)*20000 + (size_t)myidx)*256 + es_q*64); \
    _Pragma("unroll") for (int j=0;j<8;++j) eR[j]=ep[j]; }
#define K2_WRITE_E() if (tid < 384) {                                                      \
    uint4* eq = (uint4*)&e_s[es_row][es_q*64];                                             \
    _Pragma("unroll") for (int j=0;j<8;++j) eq[j]=eR[j]; }
#define K2_LOAD_D(KQ) {                                                                    \
    const uint4* dp = (const uint4*)(wdt + (size_t)ws_row*512 + (KQ)*64 + ws_h*32);        \
    wR[0]=dp[0]; wR[1]=dp[1]; wR[2]=dp[2]; wR[3]=dp[3]; }
#define K2_MFMAQ(KQ)                                                                       \
  _Pragma("unroll")                                                                        \
  for (int kk2 = 0; kk2 < 2; ++kk2) {                                                      \
    half8 bf0 = *(const half8*)&h_s[16*(3*np2+0) + l16][64*(KQ) + 32*kk2 + 8*lq];          \
    half8 bf1 = *(const half8*)&h_s[16*(3*np2+1) + l16][64*(KQ) + 32*kk2 + 8*lq];          \
    half8 bf2 = *(const half8*)&h_s[16*(3*np2+2) + l16][64*(KQ) + 32*kk2 + 8*lq];          \
    _Pragma("unroll")                                                                      \
    for (int g = 0; g < 4; ++g) {                                                          \
      half8 af = *(const half8*)&w_s[64*g + 16*hq + l16][32*kk2 + 8*lq];                   \
      acc[g][0] = MFMA16(af, bf0, acc[g][0]);                                              \
      acc[g][1] = MFMA16(af, bf1, acc[g][1]);                                              \
      acc[g][2] = MFMA16(af, bf2, acc[g][2]);                                              \
    }                                                                                      \
  }

__global__ __launch_bounds__(512, 2) void k2_main(
    const int* __restrict__ x, const float* __restrict__ bd,
    const float* __restrict__ att, const _Float16* __restrict__ embw,
    const _Float16* __restrict__ wrtb, const _Float16* __restrict__ wdt,
    float* __restrict__ out)
{
  __shared__ _Float16 h_s[96][264];   // h state, fp16, padded (+8) for bank spread
  __shared__ _Float16 w_s[256][72];   // WrT K-quarter / WdT K-slice staging
  __shared__ _Float16 e_s[96][264];   // gathered embW chunk; reused as dense^T store
  __shared__ int   xidx[96];
  __shared__ float att_s[256];
  __shared__ float wgt[48];

  const int b   = blockIdx.x;
  const int tid = threadIdx.x;
  const int wv  = tid >> 6;
  const int ln  = tid & 63;
  const int l16 = ln & 15;
  const int lq  = ln >> 4;
  const int hq  = wv & 3;     // hcol 16-subtile within chunk
  const int np2 = wv >> 2;    // 0: fw tiles (rows 0..47), 1: bw tiles (rows 48..95)
  const int es_row = tid >> 2, es_q = tid & 3;
  const int ws_row = tid >> 1, ws_h = tid & 1;

  {
    unsigned* hz = (unsigned*)&h_s[0][0];
    for (int i = tid; i < (96*264)/2; i += 512) hz[i] = 0u;
    if (tid < 256) att_s[tid] = att[tid];
  }
  __syncthreads();

  float c_reg[4][3][4];
  #pragma unroll
  for (int a1=0;a1<4;++a1)
    #pragma unroll
    for (int a2=0;a2<3;++a2)
      #pragma unroll
      for (int a3=0;a3<4;++a3) c_reg[a1][a2][a3] = 0.0f;

  uint4 eR[8], wR[4];

  for (int t = 0; t < 12; ++t) {
    if (tid < 96) {
      int s = tid;
      int praw = (s < 48) ? s : s - 48;
      int p  = (praw < 40) ? praw : 39;          // dummy rows mirror path 39
      int tt = (s < 48) ? t : (11 - t);          // bw consumes reversed time
      xidx[s] = x[(b*40 + p)*12 + tt];
    }
    __syncthreads();
    const int myidx = (tid < 384) ? xidx[es_row] : 0;
    half4v hstash[4][3];

    #pragma unroll
    for (int jt = 0; jt < 4; ++jt) {            // 4 chunks of 64 hcols
      if (jt == 0) { K2_LOAD_E(0); K2_LOAD_W(0, 0); }
      K2_WRITE_E();
      K2_WRITE_W();
      __syncthreads();
      K2_LOAD_W(jt, 1);

      f32x4 acc[4][3];                           // acc-init = gathered xg (embW rows)
      #pragma unroll
      for (int g = 0; g < 4; ++g)
        #pragma unroll
        for (int nt = 0; nt < 3; ++nt) {
          half4v ev = *(const half4v*)&e_s[16*(3*np2+nt) + l16][64*g + 16*hq + 4*lq];
          f32x4 a0;
          a0[0]=(float)ev[0]; a0[1]=(float)ev[1]; a0[2]=(float)ev[2]; a0[3]=(float)ev[3];
          acc[g][nt] = a0;
        }
      K2_MFMAQ(0);
      #pragma unroll
      for (int kq = 1; kq < 4; ++kq) {           // K quarters of 64
        __syncthreads();
        K2_WRITE_W();
        __syncthreads();
        if (kq < 3) { K2_LOAD_W(jt, kq+1); }
        else if (jt < 3) { K2_LOAD_E(jt+1); K2_LOAD_W(jt+1, 0); }
        K2_MFMAQ(kq);
      }
      // gates (i,f,g,o lane-local thanks to zT orientation)
      #pragma unroll
      for (int nt = 0; nt < 3; ++nt)
        #pragma unroll
        for (int r = 0; r < 4; ++r) {
          float zi = acc[0][nt][r], zf = acc[1][nt][r];
          float zg = acc[2][nt][r], zo = acc[3][nt][r];
          float cn = sig_(zf) * c_reg[jt][nt][r] + sig_(zi) * tanh_(zg);
          c_reg[jt][nt][r] = cn;
          hstash[jt][nt][r] = (_Float16)(sig_(zo) * tanh_(cn));
        }
      __syncthreads();
    }
    // commit h for next step
    #pragma unroll
    for (int jt2 = 0; jt2 < 4; ++jt2)
      #pragma unroll
      for (int nt = 0; nt < 3; ++nt)
        *(half4v*)&h_s[16*(3*np2+nt) + l16][64*jt2 + 16*hq + 4*lq] = hstash[jt2][nt];
    __syncthreads();
  }

  // ---------- dense: denseT[256 d][48 p] = tanh(WdT x stateT + bd) ----------
  f32x4 dacc[2][3];
  #pragma unroll
  for (int ml=0;ml<2;++ml)
    #pragma unroll
    for (int nt=0;nt<3;++nt){ f32x4 z0; z0[0]=0.f;z0[1]=0.f;z0[2]=0.f;z0[3]=0.f; dacc[ml][nt]=z0; }
  K2_LOAD_D(0);
  #pragma unroll
  for (int kq = 0; kq < 8; ++kq) {               // state dim 512 in 8 slices of 64
    K2_WRITE_W();
    __syncthreads();
    if (kq < 7) { K2_LOAD_D(kq+1); }
    #pragma unroll
    for (int kk2 = 0; kk2 < 2; ++kk2) {
      half8 bf0 = *(const half8*)&h_s[48*(kq>>2) + 16*0 + l16][64*(kq&3) + 32*kk2 + 8*lq];
      half8 bf1 = *(const half8*)&h_s[48*(kq>>2) + 16*1 + l16][64*(kq&3) + 32*kk2 + 8*lq];
      half8 bf2 = *(const half8*)&h_s[48*(kq>>2) + 16*2 + l16][64*(kq&3) + 32*kk2 + 8*lq];
      #pragma unroll
      for (int ml = 0; ml < 2; ++ml) {
        half8 af = *(const half8*)&w_s[16*(2*wv+ml) + l16][32*kk2 + 8*lq];
        dacc[ml][0] = MFMA16(af, bf0, dacc[ml][0]);
        dacc[ml][1] = MFMA16(af, bf1, dacc[ml][1]);
        dacc[ml][2] = MFMA16(af, bf2, dacc[ml][2]);
      }
    }
    __syncthreads();
  }
  _Float16* d_s = &e_s[0][0];                    // reuse e_s region: [256][56]
  #pragma unroll
  for (int ml = 0; ml < 2; ++ml) {
    int d0 = 16*(2*wv+ml) + 4*lq;
    float4 bv = *(const float4*)&bd[d0];
    float bvr[4] = {bv.x, bv.y, bv.z, bv.w};
    #pragma unroll
    for (int nt = 0; nt < 3; ++nt) {
      int p = 16*nt + l16;
      #pragma unroll
      for (int r = 0; r < 4; ++r) {
        float val = tanh_(dacc[ml][nt][r] + bvr[r]);
        d_s[(d0 + r)*56 + p] = (_Float16)val;
      }
    }
  }
  __syncthreads();
  // ---------- attention softmax over 40 paths + weighted sum ----------
  if (wv == 0) {
    float sc = -1e30f;
    if (ln < 40) {
      float s = 0.0f;
      for (int d = 0; d < 256; ++d) s += (float)d_s[d*56 + ln] * att_s[d];
      sc = s;
    }
    float m = sc;
    #pragma unroll
    for (int off = 32; off > 0; off >>= 1) m = fmaxf(m, __shfl_xor(m, off));
    float e = __expf(sc - m);
    float se = e;
    #pragma unroll
    for (int off = 32; off > 0; off >>= 1) se += __shfl_xor(se, off);
    if (ln < 40) wgt[ln] = e / se;
  }
  __syncthreads();
  if (tid < 256) {
    float o = 0.0f;
    #pragma unroll 8
    for (int p = 0; p < 40; ++p) o += wgt[p] * (float)d_s[tid*56 + p];
    out[b*256 + tid] = o;
  }
}

extern "C" void kernel_launch(void* const* d_in, const int* in_sizes, int n_in,
                              void* d_out, int out_size, void* d_ws, size_t ws_size,
                              hipStream_t stream)
{
  (void)in_sizes; (void)n_in; (void)out_size;
  const int*   x   = (const int*)  d_in[0];
  const float* emb = (const float*)d_in[1];
  const float* Wk  = (const float*)d_in[2];
  const float* Wr  = (const float*)d_in[3];
  const float* bi  = (const float*)d_in[4];
  const float* Wd  = (const float*)d_in[5];
  const float* bd  = (const float*)d_in[6];
  const float* att = (const float*)d_in[7];
  float* out = (float*)d_out;

  if (ws_size < 42401792u) return;   // need 42.4 MB scratch
  char* ws = (char*)d_ws;
  _Float16* embw = (_Float16*)(ws + 0);          // [4][20000][256] fp16 = 40,960,000 B
  _Float16* wrtb = (_Float16*)(ws + 40960000);   // [4][256][256]   fp16 =    524,288 B
  _Float16* wkt  = (_Float16*)(ws + 41484288);   // [1024][320]     fp16 =    655,360 B
  _Float16* wdt  = (_Float16*)(ws + 42139648);   // [256][512]      fp16 =    262,144 B

  k0_prep<<<dim3(1280), dim3(256), 0, stream>>>(Wk, Wr, Wd, wkt, wrtb, wdt);
  k1_embw<<<dim3(313), dim3(512), 0, stream>>>(emb, bi, wkt, embw);
  k2_main<<<dim3(256), dim3(512), 0, stream>>>(x, bd, att, embw, wrtb, wdt, out);
}

// Round 2
// 957.137 us; speedup vs baseline: 1.2102x; 1.2102x over previous
//
#include <hip/hip_runtime.h>

using half8  = __attribute__((ext_vector_type(8))) _Float16;
using half4v = __attribute__((ext_vector_type(4))) _Float16;
using f32x4  = __attribute__((ext_vector_type(4))) float;

#define MFMA16(a,b,c) __builtin_amdgcn_mfma_f32_16x16x32_f16((a),(b),(c),0,0,0)

__device__ __forceinline__ float fexp_(float x){ return exp2f(x * 1.4426950408889634f); }
__device__ __forceinline__ float sig_(float x){ return __builtin_amdgcn_rcpf(1.0f + fexp_(-x)); }
__device__ __forceinline__ float tanh_(float x){
  float t = fexp_(-2.0f * fabsf(x));
  float r = (1.0f - t) * __builtin_amdgcn_rcpf(1.0f + t);
  return copysignf(r, x);
}

// ---------------- K0: weight transposes / fp16 packing ----------------
__global__ void k0_prep(const float* __restrict__ Wk, const float* __restrict__ Wr,
                        const float* __restrict__ Wd, _Float16* __restrict__ wkt,
                        _Float16* __restrict__ wrtb, _Float16* __restrict__ wdt)
{
  int i = blockIdx.x * 256 + threadIdx.x;
  if (i < 1024*320) {
    int g = i / 320, k = i - g*320;
    wkt[i] = (_Float16)((k < 300) ? Wk[k*1024 + g] : 0.0f);
  }
  if (i < 4*256*256) {
    int jt = i >> 16, r = (i >> 8) & 255, k = i & 255;
    int g = ((r >> 6) << 8) + (jt << 6) + (r & 63);
    wrtb[i] = (_Float16)Wr[k*1024 + g];
  }
  if (i < 256*512) {
    int d = i >> 9, k = i & 511;
    wdt[i] = (_Float16)Wd[k*256 + d];
  }
}

// ---------------- K1: embW = emb @ Wk + b  -> embw[v][1024], col = 256*jt + 64*gate + i
__global__ __launch_bounds__(512, 2) void k1_embw(
    const float* __restrict__ emb, const float* __restrict__ bias,
    const _Float16* __restrict__ wkt, _Float16* __restrict__ embw)
{
  __shared__ _Float16 a_s[1024][40];
  __shared__ _Float16 e_s[64][40];
  const int tid = threadIdx.x;
  const int wv = tid >> 6, ln = tid & 63, l16 = ln & 15, lq = ln >> 4;
  const int v0 = blockIdx.x * 64;

  f32x4 acc[8][4];
  #pragma unroll
  for (int ml=0;ml<8;++ml)
    #pragma unroll
    for (int nt=0;nt<4;++nt){ f32x4 z0; z0[0]=0.f;z0[1]=0.f;z0[2]=0.f;z0[3]=0.f; acc[ml][nt]=z0; }

  const int evv = tid >> 2;
  const int ekq = tid & 3;

  for (int c = 0; c < 10; ++c) {
    {
      const uint4* sp  = (const uint4*)(wkt + (size_t)(2*tid)*320 + 32*c);
      uint4 r0=sp[0], r1=sp[1], r2=sp[2], r3=sp[3];
      const uint4* sp2 = (const uint4*)(wkt + (size_t)(2*tid+1)*320 + 32*c);
      uint4 r4=sp2[0], r5=sp2[1], r6=sp2[2], r7=sp2[3];
      uint4* dq  = (uint4*)&a_s[2*tid][0];
      dq[0]=r0; dq[1]=r1; dq[2]=r2; dq[3]=r3;
      uint4* dq2 = (uint4*)&a_s[2*tid+1][0];
      dq2[0]=r4; dq2[1]=r5; dq2[2]=r6; dq2[3]=r7;
    }
    if (tid < 256) {
      int vsrc = v0 + evv; if (vsrc > 19999) vsrc = 19999;
      float f0,f1,f2,f3,f4,f5,f6,f7;
      if (c < 9) {
        const float4* sp = (const float4*)(emb + (size_t)vsrc*300 + 32*c + 8*ekq);
        float4 fa = sp[0], fb = sp[1];
        f0=fa.x; f1=fa.y; f2=fa.z; f3=fa.w; f4=fb.x; f5=fb.y; f6=fb.z; f7=fb.w;
      } else {
        const float* sp = emb + (size_t)vsrc*300;
        int k0 = 288 + 8*ekq;
        f0 = (k0+0<300)? sp[k0+0] : 0.f;  f1 = (k0+1<300)? sp[k0+1] : 0.f;
        f2 = (k0+2<300)? sp[k0+2] : 0.f;  f3 = (k0+3<300)? sp[k0+3] : 0.f;
        f4 = (k0+4<300)? sp[k0+4] : 0.f;  f5 = (k0+5<300)? sp[k0+5] : 0.f;
        f6 = (k0+6<300)? sp[k0+6] : 0.f;  f7 = (k0+7<300)? sp[k0+7] : 0.f;
      }
      half8 hv;
      hv[0]=(_Float16)f0; hv[1]=(_Float16)f1; hv[2]=(_Float16)f2; hv[3]=(_Float16)f3;
      hv[4]=(_Float16)f4; hv[5]=(_Float16)f5; hv[6]=(_Float16)f6; hv[7]=(_Float16)f7;
      *(half8*)&e_s[evv][8*ekq] = hv;
    }
    __syncthreads();
    half8 bf[4];
    #pragma unroll
    for (int nt=0;nt<4;++nt) bf[nt] = *(const half8*)&e_s[16*nt + l16][8*lq];
    #pragma unroll
    for (int ml=0;ml<8;++ml) {
      half8 af = *(const half8*)&a_s[16*(8*wv+ml) + l16][8*lq];
      #pragma unroll
      for (int nt=0;nt<4;++nt) acc[ml][nt] = MFMA16(af, bf[nt], acc[ml][nt]);
    }
    __syncthreads();
  }
  #pragma unroll
  for (int ml=0;ml<8;++ml) {
    int g0 = 16*(8*wv+ml) + 4*lq;
    float4 bv = *(const float4*)&bias[g0];
    float bvr[4] = {bv.x,bv.y,bv.z,bv.w};
    int jt = (g0 >> 6) & 3;
    int c0 = ((g0 >> 8) << 6) + (g0 & 63);
    #pragma unroll
    for (int nt=0;nt<4;++nt) {
      int v = v0 + 16*nt + l16;
      if (v < 20000) {
        half4v hv;
        hv[0]=(_Float16)(acc[ml][nt][0]+bvr[0]);
        hv[1]=(_Float16)(acc[ml][nt][1]+bvr[1]);
        hv[2]=(_Float16)(acc[ml][nt][2]+bvr[2]);
        hv[3]=(_Float16)(acc[ml][nt][3]+bvr[3]);
        *(half4v*)&embw[(size_t)v*1024 + 256*jt + c0] = hv;
      }
    }
  }
}

// ---------------- K2: fused bi-LSTM + dense + attention, 1 block = 1 card ----------------
// 80 seq rows: 0..39 fw paths, 40..79 bw paths. zT = WrT(A, direct from L2) x hT(B, LDS).
// Waves: hq = wv&3 (16-col subtile), np2 = wv>>2 (row half; np2=0 -> rows 0..47 (3 nt),
// np2=1 -> rows 48..79 (2 nt)). h_s double-buffered; ONE barrier per time step.

#define NEXT_IDX(T) do { \
    _Pragma("unroll") for (int nt=0;nt<3;++nt) if (nt<NT) \
      idxc[nt] = x[xb + pA[nt]*12 + (dirA[nt] ? 11-(T) : (T))]; \
  } while(0)

#define ISSUE_E(JT) do { \
    _Pragma("unroll") for (int nt=0;nt<3;++nt) if (nt<NT) { \
      const _Float16* ep = embw + (size_t)idxc[nt]*1024 + 256*(JT) + ebase; \
      _Pragma("unroll") for (int g=0;g<4;++g) eR[g][nt] = *(const half4v*)(ep + 64*g); \
    } } while(0)

#define ACC_FROM_E() do { \
    _Pragma("unroll") for (int g=0;g<4;++g) \
      _Pragma("unroll") for (int nt=0;nt<3;++nt) if (nt<NT) { \
        f32x4 a0; a0[0]=(float)eR[g][nt][0]; a0[1]=(float)eR[g][nt][1]; \
        a0[2]=(float)eR[g][nt][2]; a0[3]=(float)eR[g][nt][3]; acc[g][nt]=a0; \
      } } while(0)

#define ISSUE_A(P,JT,KQ) do { \
    const _Float16* ap = wrtb + abase + 65536*(JT) + 64*(KQ); \
    _Pragma("unroll") for (int g=0;g<4;++g) { \
      aR[P][2*g+0] = *(const half8*)(ap + 16384*g); \
      aR[P][2*g+1] = *(const half8*)(ap + 16384*g + 32); \
    } } while(0)

#define MFMAQ(P,KQ) do { \
    _Pragma("unroll") for (int kk2=0;kk2<2;++kk2) { \
      half8 bF[3]; \
      _Pragma("unroll") for (int nt=0;nt<3;++nt) if (nt<NT) \
        bF[nt] = *(const half8*)(hc + bbase[nt] + ((64*(KQ)+32*kk2+8*lq) ^ bswz[nt])); \
      _Pragma("unroll") for (int g=0;g<4;++g) \
        _Pragma("unroll") for (int nt=0;nt<3;++nt) if (nt<NT) \
          acc[g][nt] = MFMA16(aR[P][2*g+kk2], bF[nt], acc[g][nt]); \
    } } while(0)

#define GATES(JT) do { \
    _Pragma("unroll") for (int nt=0;nt<3;++nt) if (nt<NT) { \
      half4v hv; \
      _Pragma("unroll") for (int r=0;r<4;++r) { \
        float zi=acc[0][nt][r], zf=acc[1][nt][r], zg=acc[2][nt][r], zo=acc[3][nt][r]; \
        float cn = sig_(zf)*c_reg[JT][nt][r] + sig_(zi)*tanh_(zg); \
        c_reg[JT][nt][r]=cn; hv[r]=(_Float16)(sig_(zo)*tanh_(cn)); \
      } \
      *(half4v*)(hn + bbase[nt] + ((64*(JT)+16*hq+4*lq) ^ bswz[nt])) = hv; \
    } } while(0)

__global__ __launch_bounds__(512, 2) void k2_main(
    const int* __restrict__ x, const float* __restrict__ bd,
    const float* __restrict__ att, const _Float16* __restrict__ embw,
    const _Float16* __restrict__ wrtb, const _Float16* __restrict__ wdt,
    float* __restrict__ out)
{
  __shared__ _Float16 h_s[2][80][256];
  __shared__ float att_s[256];
  __shared__ float sc_s[40];
  __shared__ float wgt[40];

  const int b   = blockIdx.x;
  const int tid = threadIdx.x;
  const int wv  = tid >> 6;
  const int ln  = tid & 63;
  const int l16 = ln & 15;
  const int lq  = ln >> 4;
  const int hq  = wv & 3;
  const int np2 = wv >> 2;
  const int NT  = np2 ? 2 : 3;

  if (tid < 256) att_s[tid] = att[tid];

  int srow[3] = {0,0,0}, pA[3] = {0,0,0}, dirA[3] = {0,0,0};
  int bbase[3] = {0,0,0}, bswz[3] = {0,0,0};
  #pragma unroll
  for (int nt=0;nt<3;++nt) if (nt<NT) {
    int s = 48*np2 + 16*nt + l16;
    srow[nt] = s; dirA[nt] = (s >= 40); pA[nt] = s - 40*(s>=40);
    bbase[nt] = s*256; bswz[nt] = (s&7)<<3;
  }
  const int xb = b*480;
  const int ebase = 16*hq + 4*lq;
  const size_t abase = (size_t)(16*hq + l16)*256 + 8*lq;

  float c_reg[4][3][4];
  #pragma unroll
  for (int a1=0;a1<4;++a1)
    #pragma unroll
    for (int a2=0;a2<3;++a2)
      #pragma unroll
      for (int a3=0;a3<4;++a3) c_reg[a1][a2][a3] = 0.0f;

  half4v eR[4][3];
  half8  aR[2][8];
  f32x4  acc[4][3];
  int idxc[3] = {0,0,0};

  NEXT_IDX(0);
  ISSUE_E(0);

  for (int t = 0; t < 12; ++t) {
    const _Float16* hc = &h_s[t&1][0][0];
    _Float16*       hn = &h_s[(t+1)&1][0][0];
    const bool first = (t == 0), last = (t == 11);
    #pragma unroll
    for (int jt = 0; jt < 4; ++jt) {
      ACC_FROM_E();
      if (jt < 3) { ISSUE_E(jt+1); }
      else if (!last) { NEXT_IDX(t+1); ISSUE_E(0); }
      if (!first) {
        #pragma unroll
        for (int kq = 0; kq < 4; ++kq) {
          if (kq < 3)      { ISSUE_A((kq&1)^1, jt, kq+1); }
          else if (jt < 3) { ISSUE_A((kq&1)^1, jt+1, 0); }
          else if (!last)  { ISSUE_A((kq&1)^1, 0, 0); }
          MFMAQ(kq&1, kq);
        }
      } else if (jt == 3) {
        ISSUE_A(0, 0, 0);   // prime A pipeline for t=1
      }
      GATES(jt);
    }
    __syncthreads();
  }

  // ---------- dense: denseT[256 d][48 p] = tanh(WdT x stateT + bd), barrier-free ----------
  const _Float16* hs0 = &h_s[0][0][0];   // final state lives in buf 0
  f32x4 dacc[2][3];
  #pragma unroll
  for (int ml=0;ml<2;++ml)
    #pragma unroll
    for (int nt=0;nt<3;++nt){ f32x4 z0; z0[0]=0.f;z0[1]=0.f;z0[2]=0.f;z0[3]=0.f; dacc[ml][nt]=z0; }
  int pD2[3];
  #pragma unroll
  for (int nt=0;nt<3;++nt){ int p = 16*nt + l16; pD2[nt] = (p < 40) ? p : 39; }

  #pragma unroll
  for (int kq = 0; kq < 8; ++kq) {
    const _Float16* wp0 = wdt + (size_t)(16*(2*wv+0)+l16)*512 + 64*kq + 8*lq;
    const _Float16* wp1 = wdt + (size_t)(16*(2*wv+1)+l16)*512 + 64*kq + 8*lq;
    half8 ad0a = *(const half8*)(wp0), ad0b = *(const half8*)(wp0 + 32);
    half8 ad1a = *(const half8*)(wp1), ad1b = *(const half8*)(wp1 + 32);
    #pragma unroll
    for (int kk2=0;kk2<2;++kk2) {
      half8 bD[3];
      #pragma unroll
      for (int nt=0;nt<3;++nt) {
        int rowD = pD2[nt] + 40*(kq>>2);
        bD[nt] = *(const half8*)(hs0 + rowD*256 + ((64*(kq&3)+32*kk2+8*lq) ^ ((rowD&7)<<3)));
      }
      half8 a0 = kk2 ? ad0b : ad0a;
      half8 a1 = kk2 ? ad1b : ad1a;
      #pragma unroll
      for (int nt=0;nt<3;++nt) {
        dacc[0][nt] = MFMA16(a0, bD[nt], dacc[0][nt]);
        dacc[1][nt] = MFMA16(a1, bD[nt], dacc[1][nt]);
      }
    }
  }
  _Float16* d_s = (_Float16*)&h_s[1][0][0];   // overlay dead buffer: [256 d][56]
  #pragma unroll
  for (int ml = 0; ml < 2; ++ml) {
    int d0 = 16*(2*wv+ml) + 4*lq;
    float4 bv = *(const float4*)&bd[d0];
    float bvr[4] = {bv.x, bv.y, bv.z, bv.w};
    #pragma unroll
    for (int nt = 0; nt < 3; ++nt) {
      int p = 16*nt + l16;
      #pragma unroll
      for (int r = 0; r < 4; ++r) {
        float val = tanh_(dacc[ml][nt][r] + bvr[r]);
        d_s[(d0 + r)*56 + p] = (_Float16)val;
      }
    }
  }
  __syncthreads();
  // ---------- attention: scores by all 8 waves (5 paths each), softmax, weighted sum ----------
  {
    #pragma unroll
    for (int q = 0; q < 5; ++q) {
      int pp = 5*wv + q;
      float s = 0.0f;
      #pragma unroll
      for (int j = 0; j < 4; ++j) {
        int d = 64*j + ln;
        s += (float)d_s[d*56 + pp] * att_s[d];
      }
      #pragma unroll
      for (int off = 32; off > 0; off >>= 1) s += __shfl_xor(s, off);
      if (ln == 0) sc_s[pp] = s;
    }
  }
  __syncthreads();
  if (wv == 0) {
    float sc = (ln < 40) ? sc_s[ln] : -1e30f;
    float m = sc;
    #pragma unroll
    for (int off = 32; off > 0; off >>= 1) m = fmaxf(m, __shfl_xor(m, off));
    float e = __expf(sc - m);
    float se = e;
    #pragma unroll
    for (int off = 32; off > 0; off >>= 1) se += __shfl_xor(se, off);
    if (ln < 40) wgt[ln] = e / se;
  }
  __syncthreads();
  if (tid < 256) {
    float o = 0.0f;
    #pragma unroll 8
    for (int p = 0; p < 40; ++p) o += wgt[p] * (float)d_s[tid*56 + p];
    out[b*256 + tid] = o;
  }
}

extern "C" void kernel_launch(void* const* d_in, const int* in_sizes, int n_in,
                              void* d_out, int out_size, void* d_ws, size_t ws_size,
                              hipStream_t stream)
{
  (void)in_sizes; (void)n_in; (void)out_size;
  const int*   x   = (const int*)  d_in[0];
  const float* emb = (const float*)d_in[1];
  const float* Wk  = (const float*)d_in[2];
  const float* Wr  = (const float*)d_in[3];
  const float* bi  = (const float*)d_in[4];
  const float* Wd  = (const float*)d_in[5];
  const float* bd  = (const float*)d_in[6];
  const float* att = (const float*)d_in[7];
  float* out = (float*)d_out;

  if (ws_size < 42401792u) return;   // need 42.4 MB scratch
  char* ws = (char*)d_ws;
  _Float16* embw = (_Float16*)(ws + 0);          // [20000][1024] fp16 = 40,960,000 B
  _Float16* wrtb = (_Float16*)(ws + 40960000);   // [4][256][256] fp16 =    524,288 B
  _Float16* wkt  = (_Float16*)(ws + 41484288);   // [1024][320]   fp16 =    655,360 B
  _Float16* wdt  = (_Float16*)(ws + 42139648);   // [256][512]    fp16 =    262,144 B

  k0_prep<<<dim3(1280), dim3(256), 0, stream>>>(Wk, Wr, Wd, wkt, wrtb, wdt);
  k1_embw<<<dim3(313), dim3(512), 0, stream>>>(emb, bi, wkt, embw);
  k2_main<<<dim3(256), dim3(512), 0, stream>>>(x, bd, att, embw, wrtb, wdt, out);
}